// Round 12
// baseline (5185.621 us; speedup 1.0000x reference)
//
#include <hip/hip_runtime.h>
#include <hip/hip_bf16.h>
#include <stdint.h>

// Problem dims
#define BB 64     // batch
#define SS 512    // seq len
#define HH 512    // hidden
#define DD 300    // embed dim
#define DP 320    // embed dim padded to K%32==0

typedef __attribute__((ext_vector_type(8))) short short8;      // 8 x bf16
typedef __attribute__((ext_vector_type(4))) float f32x4;

__device__ __forceinline__ unsigned short f2bf(float f) {
  unsigned u = __builtin_bit_cast(unsigned, f);
  u += 0x7fffu + ((u >> 16) & 1u);       // RNE
  return (unsigned short)(u >> 16);
}
__device__ __forceinline__ float sigm(float x) { return 1.f / (1.f + __expf(-x)); }
__device__ __forceinline__ float tanh_f(float x) {
  float t = __expf(-2.f * fabsf(x));
  float r = (1.f - t) / (1.f + t);
  return x < 0.f ? -r : r;
}

// 16B loads. Cached (L2) variant for h/xe data; results NOT valid until vmcnt(0).
__device__ __forceinline__ short8 load_frag(const unsigned short* p) {
  short8 r;
  asm volatile("global_load_dwordx4 %0, %1, off" : "=v"(r) : "v"(p));
  return r;
}
__device__ __forceinline__ unsigned ld_seq(const unsigned int* p) {
  return __hip_atomic_load(p, __ATOMIC_RELAXED, __HIP_MEMORY_SCOPE_AGENT);
}
__device__ __forceinline__ void st_seq(unsigned int* p, unsigned v) {
  __hip_atomic_store(p, v, __ATOMIC_RELAXED, __HIP_MEMORY_SCOPE_AGENT);
}

// ---------------- workspace layout (bytes) ----------------
// h panels: ONE 64KB slot PER TIMESTEP (no reuse => consumer L2 lines are
// virgin => cached reads are safe; the XCD L2 becomes a broadcast tree and
// cuts the 128-way same-line MALL read storm ~16x, which r4-r11 shared).
// h(t) lives at slot t+1; slot 0 = zeros = h(-1).
// Frag-ready panel layout: element (b,c) at u16 addr (c>>5)*2048 + (b>>4)*512
// + ((c>>3)&3)*128 + (b&15)*8 + (c&7); A-frag (m,kblk) = kblk*2048+m*512+lane*8.
// Producers store h with sc1 (write-through to MALL) + vmcnt drain + seq store;
// consumers poll seq (sc1) then load h CACHED.
#define OFF_SEQ   0u          // h1seq[64] @0, l1seq[64] @4096 (64B spaced) -> 8192
#define OFF_H1    8192u       // h1 [513][32768 u16] -> 33619968
#define OFF_H2    33628160u   // h2 [513][32768 u16] -> 33619968
#define OFF_C2    67248128u   // c2 [64][512] f32 -> 131072
#define OFF_XE    67379200u   // xe bf16 frag layout [512][20480 u16] -> 20971520
#define OFF_W0    88350720u   // Wp0 [2048][832] bf16 -> 3407872
#define OFF_W1    91758592u   // Wp1 [2048][1024] bf16 -> 4194304
#define OFF_B0    95952896u   // bias0p [2048] f32
#define OFF_B1    95961088u   // bias1p [2048] f32

// ---------------- weight prep (row-major Wp) ----------------
// grow = lblk*32 + l, gate = l>>3 (i,f,g,o), orig = gate*512 + lblk*8 + (l&7).
// Wp0 row: [ W_hh0 | W_ih0 | pad ] (A = [h1_prev | x_t]); Wp1 row: [ W_ih1 | W_hh1 ].
__global__ void prep_weights(const float* __restrict__ Wih0, const float* __restrict__ Whh0,
                             const float* __restrict__ bih0, const float* __restrict__ bhh0,
                             const float* __restrict__ Wih1, const float* __restrict__ Whh1,
                             const float* __restrict__ bih1, const float* __restrict__ bhh1,
                             unsigned short* __restrict__ Wp0, unsigned short* __restrict__ Wp1,
                             float* __restrict__ b0p, float* __restrict__ b1p)
{
  int idx = blockIdx.x * 256 + threadIdx.x;   // over 2048*1024
  int grow = idx >> 10;
  int k1 = idx & 1023;
  int l = grow & 31;
  int lb = grow >> 5;
  int gate = l >> 3;
  int orig = gate * 512 + lb * 8 + (l & 7);
  float v1 = (k1 < 512) ? Wih1[orig * 512 + k1] : Whh1[orig * 512 + (k1 - 512)];
  Wp1[idx] = f2bf(v1);
  if (k1 < 832) {
    float v0;
    if (k1 < 512)      v0 = Whh0[orig * 512 + k1];
    else if (k1 < 812) v0 = Wih0[orig * 300 + (k1 - 512)];
    else               v0 = 0.f;
    Wp0[grow * 832 + k1] = f2bf(v0);
  }
  if (k1 == 0) {
    b0p[grow] = bih0[orig] + bhh0[orig];
    b1p[grow] = bih1[orig] + bhh1[orig];
  }
}

// ---------------- embedding gather -> bf16 frag layout ----------------
__global__ void gather_xe(const int* __restrict__ x, const float* __restrict__ emb,
                          unsigned short* __restrict__ xe)
{
  int idx = blockIdx.x * 256 + threadIdx.x;   // SS*BB*DP = 10485760
  int dk = idx % DP;
  int rem = idx / DP;
  int b = rem % BB;
  int t = rem / BB;
  int tok = x[b * SS + t];
  float v = (dk < DD) ? emb[(size_t)tok * DD + dk] : 0.f;
  size_t ua = (size_t)t * 20480 + (size_t)(dk >> 5) * 2048 + (size_t)(b >> 4) * 512
            + (size_t)((dk >> 3) & 3) * 128 + (size_t)(b & 15) * 8 + (dk & 7);
  xe[ua] = f2bf(v);
}

// ---------------- layer-0 persistent scan (64 blocks) ----------------
// Step t: wait all h1seq >= t (peers stored h1(t-1) at slot t), cached-load
// h1(t-1) + xe(t), MFMA, pointwise, sc1-store h1(t) at slot t+1, drain,
// barrier, h1seq = t+1. No back-pressure: slots are never reused.
__device__ __forceinline__ void scan_l0(
    int lblk,
    const unsigned short* __restrict__ xe,
    const unsigned short* __restrict__ Wp,
    const float* __restrict__ biasP,
    unsigned short* __restrict__ h1r,
    unsigned int* __restrict__ h1seq,
    float (&gl)[2][2][64][36], float (&bias_sm)[32])
{
  constexpr int K = 832;
  const int tid  = threadIdx.x;
  const int lane = tid & 63;
  const int wave = tid >> 6;
  const int lrow = lane & 15;
  const int m    = wave & 3;
  const int q    = wave >> 2;
  const int qkb  = q * 13;

  if (tid < 32) bias_sm[tid] = biasP[lblk * 32 + tid];

  const unsigned short* wr0 = Wp + (size_t)(lblk * 32 + lrow) * K + qkb * 32 + (lane >> 4) * 8;
  const unsigned short* wr1 = wr0 + (size_t)16 * K;

  float creg = 0.f;
  const int pb = tid >> 3;
  const int ph = tid & 7;
  const size_t hstu = (size_t)(lblk >> 2) * 2048 + (size_t)(pb >> 4) * 512
                    + (size_t)(lblk & 3) * 128 + (size_t)(pb & 15) * 8 + ph;

  for (int t = 0; t < 512; ++t) {
    short8 a[13];
    // xe prefetch (cached, static) before the wait
    if (q == 1) {
      const unsigned short* xet = xe + (size_t)t * 20480;
      #pragma unroll
      for (int j = 3; j < 13; ++j)
        a[j] = load_frag(xet + (size_t)(qkb + j - 16) * 2048 + (size_t)m * 512 + lane * 8);
    }
    if (t >= 1) {
      if (wave == 0) {
        int guard = 0;
        for (;;) {
          unsigned v = ld_seq(h1seq + lane * 16);
          if (__all(v >= (unsigned)t)) break;
          if (++guard > (1 << 18)) break;   // liveness insurance
          __builtin_amdgcn_s_sleep(1);
        }
      }
      __syncthreads();
    }
    // h1(t-1) cached loads from slot t (virgin lines; XCD L2 broadcasts)
    {
      const unsigned short* hA = h1r + (size_t)t * 32768;
      #pragma unroll
      for (int j = 0; j < 13; ++j) {
        const int kg = qkb + j;
        if (kg < 16)
          a[j] = load_frag(hA + (size_t)kg * 2048 + (size_t)m * 512 + lane * 8);
      }
    }
    asm volatile("s_waitcnt vmcnt(0)" ::: "memory");
    __builtin_amdgcn_sched_barrier(0);

    f32x4 acc0 = {0.f, 0.f, 0.f, 0.f};
    f32x4 acc1 = {0.f, 0.f, 0.f, 0.f};
    #pragma unroll
    for (int j = 0; j < 13; ++j) {
      short8 b0 = *(const short8*)(wr0 + j * 32);
      short8 b1 = *(const short8*)(wr1 + j * 32);
      acc0 = __builtin_amdgcn_mfma_f32_16x16x32_bf16(a[j], b0, acc0, 0, 0, 0);
      acc1 = __builtin_amdgcn_mfma_f32_16x16x32_bf16(a[j], b1, acc1, 0, 0, 0);
    }
    #pragma unroll
    for (int r = 0; r < 4; ++r) {
      const int bb = m * 16 + (lane >> 4) * 4 + r;
      gl[t & 1][q][bb][lrow]      = acc0[r];
      gl[t & 1][q][bb][16 + lrow] = acc1[r];
    }
    __syncthreads();
    {
      const float* g0 = gl[t & 1][0][pb];
      const float* g1 = gl[t & 1][1][pb];
      float gi = g0[ph]      + g1[ph]      + bias_sm[ph];
      float gf = g0[8 + ph]  + g1[8 + ph]  + bias_sm[8 + ph];
      float gg = g0[16 + ph] + g1[16 + ph] + bias_sm[16 + ph];
      float go = g0[24 + ph] + g1[24 + ph] + bias_sm[24 + ph];
      float iv = sigm(gi), fv = sigm(gf), ov = sigm(go), gv = tanh_f(gg);
      creg = fv * creg + iv * gv;
      float hv = ov * tanh_f(creg);
      unsigned short hb = f2bf(hv);
      unsigned pair = (unsigned)hb | ((unsigned)(unsigned short)__shfl_down((int)hb, 1) << 16);
      if ((ph & 1) == 0)
        st_seq((unsigned*)(h1r + (size_t)(t + 1) * 32768 + hstu), pair);  // sc1 store
    }
    asm volatile("s_waitcnt vmcnt(0)" ::: "memory");   // h1(t) in MALL
    __syncthreads();                                    // all waves drained
    if (tid == 0) st_seq(h1seq + lblk * 16, (unsigned)(t + 1));
  }
}

// ---------------- layer-1 persistent scan (64 blocks) ----------------
// Step t: wave0 polls h1seq >= t+1 -> S1 -> q=0 cached-loads h1(t) (slot t+1)
// + MFMA while wave4 polls l1seq >= t -> S2 -> q=1 cached-loads h2(t-1)
// (slot t) + MFMA -> S3 -> pointwise -> sc1 h2 store slot t+1 -> drain -> S4
// -> l1seq = t+1.
__device__ __forceinline__ void scan_l1(
    int lblk,
    const unsigned short* __restrict__ Wp,
    const float* __restrict__ biasP,
    const unsigned short* __restrict__ h1r,
    unsigned short* __restrict__ h2r,
    float* __restrict__ c2,
    unsigned int* __restrict__ h1seq, unsigned int* __restrict__ l1seq,
    float (&gl)[2][2][64][36], float (&bias_sm)[32])
{
  constexpr int K = 1024;
  const int tid  = threadIdx.x;
  const int lane = tid & 63;
  const int wave = tid >> 6;
  const int lrow = lane & 15;
  const int m    = wave & 3;
  const int q    = wave >> 2;
  const int qkb  = q * 16;

  if (tid < 32) bias_sm[tid] = biasP[lblk * 32 + tid];

  const unsigned short* wr0 = Wp + (size_t)(lblk * 32 + lrow) * K + qkb * 32 + (lane >> 4) * 8;
  const unsigned short* wr1 = wr0 + (size_t)16 * K;

  float creg = 0.f;
  const int pb = tid >> 3;
  const int ph = tid & 7;
  const size_t hstu = (size_t)(lblk >> 2) * 2048 + (size_t)(pb >> 4) * 512
                    + (size_t)(lblk & 3) * 128 + (size_t)(pb & 15) * 8 + ph;

  for (int t = 0; t < 512; ++t) {
    // ---- phase A: wait for h1(t) ----
    if (wave == 0) {
      int guard = 0;
      for (;;) {
        unsigned v = ld_seq(h1seq + lane * 16);
        if (__all(v >= (unsigned)(t + 1))) break;
        if (++guard > (1 << 18)) break;
        __builtin_amdgcn_s_sleep(1);
      }
    }
    __syncthreads();   // S1

    if (q == 0) {
      const unsigned short* hA = h1r + (size_t)(t + 1) * 32768;
      short8 a[16];
      #pragma unroll
      for (int j = 0; j < 16; ++j)
        a[j] = load_frag(hA + (size_t)j * 2048 + (size_t)m * 512 + lane * 8);
      asm volatile("s_waitcnt vmcnt(0)" ::: "memory");
      __builtin_amdgcn_sched_barrier(0);
      f32x4 acc0 = {0.f, 0.f, 0.f, 0.f};
      f32x4 acc1 = {0.f, 0.f, 0.f, 0.f};
      #pragma unroll
      for (int j = 0; j < 16; ++j) {
        short8 b0 = *(const short8*)(wr0 + j * 32);
        short8 b1 = *(const short8*)(wr1 + j * 32);
        acc0 = __builtin_amdgcn_mfma_f32_16x16x32_bf16(a[j], b0, acc0, 0, 0, 0);
        acc1 = __builtin_amdgcn_mfma_f32_16x16x32_bf16(a[j], b1, acc1, 0, 0, 0);
      }
      #pragma unroll
      for (int r = 0; r < 4; ++r) {
        const int bb = m * 16 + (lane >> 4) * 4 + r;
        gl[t & 1][0][bb][lrow]      = acc0[r];
        gl[t & 1][0][bb][16 + lrow] = acc1[r];
      }
    } else if (wave == 4) {
      if (t >= 1) {
        int guard = 0;
        for (;;) {
          unsigned v = ld_seq(l1seq + lane * 16);
          if (__all(v >= (unsigned)t)) break;
          if (++guard > (1 << 18)) break;
          __builtin_amdgcn_s_sleep(1);
        }
      }
    }
    __syncthreads();   // S2: h2(t-1) ready everywhere

    if (q == 1) {
      const unsigned short* hB = h2r + (size_t)t * 32768;
      short8 a[16];
      #pragma unroll
      for (int j = 0; j < 16; ++j)
        a[j] = load_frag(hB + (size_t)j * 2048 + (size_t)m * 512 + lane * 8);
      asm volatile("s_waitcnt vmcnt(0)" ::: "memory");
      __builtin_amdgcn_sched_barrier(0);
      f32x4 acc0 = {0.f, 0.f, 0.f, 0.f};
      f32x4 acc1 = {0.f, 0.f, 0.f, 0.f};
      #pragma unroll
      for (int j = 0; j < 16; ++j) {
        short8 b0 = *(const short8*)(wr0 + j * 32);
        short8 b1 = *(const short8*)(wr1 + j * 32);
        acc0 = __builtin_amdgcn_mfma_f32_16x16x32_bf16(a[j], b0, acc0, 0, 0, 0);
        acc1 = __builtin_amdgcn_mfma_f32_16x16x32_bf16(a[j], b1, acc1, 0, 0, 0);
      }
      #pragma unroll
      for (int r = 0; r < 4; ++r) {
        const int bb = m * 16 + (lane >> 4) * 4 + r;
        gl[t & 1][1][bb][lrow]      = acc0[r];
        gl[t & 1][1][bb][16 + lrow] = acc1[r];
      }
    }
    __syncthreads();   // S3

    {
      const float* g0 = gl[t & 1][0][pb];
      const float* g1 = gl[t & 1][1][pb];
      float gi = g0[ph]      + g1[ph]      + bias_sm[ph];
      float gf = g0[8 + ph]  + g1[8 + ph]  + bias_sm[8 + ph];
      float gg = g0[16 + ph] + g1[16 + ph] + bias_sm[16 + ph];
      float go = g0[24 + ph] + g1[24 + ph] + bias_sm[24 + ph];
      float iv = sigm(gi), fv = sigm(gf), ov = sigm(go), gv = tanh_f(gg);
      creg = fv * creg + iv * gv;
      float hv = ov * tanh_f(creg);
      unsigned short hb = f2bf(hv);
      unsigned pair = (unsigned)hb | ((unsigned)(unsigned short)__shfl_down((int)hb, 1) << 16);
      if ((ph & 1) == 0)
        st_seq((unsigned*)(h2r + (size_t)(t + 1) * 32768 + hstu), pair);  // sc1 store
      if (t == 511) c2[pb * HH + lblk * 8 + ph] = creg;
    }
    asm volatile("s_waitcnt vmcnt(0)" ::: "memory");   // h2(t) in MALL
    __syncthreads();   // S4
    if (tid == 0) st_seq(l1seq + lblk * 16, (unsigned)(t + 1));
  }
}

__attribute__((amdgpu_waves_per_eu(2, 2)))
__global__ void __launch_bounds__(512)
lstm_scan(const unsigned short* __restrict__ xe,
          const unsigned short* __restrict__ Wp0,
          const unsigned short* __restrict__ Wp1,
          const float* __restrict__ b0p, const float* __restrict__ b1p,
          unsigned short* __restrict__ h1r, unsigned short* __restrict__ h2r,
          float* __restrict__ c2, unsigned int* __restrict__ seqbase)
{
  __shared__ float gl[2][2][64][36];   // [step parity][khalf][batch][gate col]
  __shared__ float bias_sm[32];
  unsigned int* h1seq = seqbase;
  unsigned int* l1seq = seqbase + 1024;   // byte 4096
  const int blk = blockIdx.x;
  if (blk < 64) scan_l0(blk,      xe, Wp0, b0p, h1r, h1seq, gl, bias_sm);
  else          scan_l1(blk - 64, Wp1, b1p, h1r, h2r, c2, h1seq, l1seq, gl, bias_sm);
}

// ---------------- final projection: out = c2 @ Wout^T + bout ----------------
__global__ void outproj(const float* __restrict__ c2, const float* __restrict__ Wout,
                        const float* __restrict__ bout, float* __restrict__ out)
{
  int t = threadIdx.x;
  if (t >= 640) return;
  int b = t / 10, l = t % 10;
  float s = bout[l];
  #pragma unroll 8
  for (int h = 0; h < 512; ++h) s += c2[b * 512 + h] * Wout[l * 512 + h];
  out[b * 10 + l] = s;
}

extern "C" void kernel_launch(void* const* d_in, const int* in_sizes, int n_in,
                              void* d_out, int out_size, void* d_ws, size_t ws_size,
                              hipStream_t stream) {
  (void)in_sizes; (void)n_in; (void)out_size; (void)ws_size;
  const int*   x    = (const int*)  d_in[0];
  const float* emb  = (const float*)d_in[1];
  const float* Wih0 = (const float*)d_in[2];
  const float* Whh0 = (const float*)d_in[3];
  const float* bih0 = (const float*)d_in[4];
  const float* bhh0 = (const float*)d_in[5];
  const float* Wih1 = (const float*)d_in[6];
  const float* Whh1 = (const float*)d_in[7];
  const float* bih1 = (const float*)d_in[8];
  const float* bhh1 = (const float*)d_in[9];
  const float* Wout = (const float*)d_in[10];
  const float* bout = (const float*)d_in[11];
  float* out = (float*)d_out;

  char* ws = (char*)d_ws;
  unsigned int*   seqb = (unsigned int*)  (ws + OFF_SEQ);
  unsigned short* h1r  = (unsigned short*)(ws + OFF_H1);
  unsigned short* h2r  = (unsigned short*)(ws + OFF_H2);
  float*          c2   = (float*)         (ws + OFF_C2);
  unsigned short* xe   = (unsigned short*)(ws + OFF_XE);
  unsigned short* Wp0  = (unsigned short*)(ws + OFF_W0);
  unsigned short* Wp1  = (unsigned short*)(ws + OFF_W1);
  float*          b0p  = (float*)         (ws + OFF_B0);
  float*          b1p  = (float*)         (ws + OFF_B1);

  // Per-launch init: seq words + the h(-1) zero slots only (slot 0 of each
  // panel chain). All other slots are write-before-read by construction.
  hipMemsetAsync(ws + OFF_SEQ, 0, 8192,  stream);
  hipMemsetAsync(ws + OFF_H1,  0, 65536, stream);
  hipMemsetAsync(ws + OFF_H2,  0, 65536, stream);

  prep_weights<<<8192, 256, 0, stream>>>(Wih0, Whh0, bih0, bhh0, Wih1, Whh1, bih1, bhh1,
                                         Wp0, Wp1, b0p, b1p);
  gather_xe<<<40960, 256, 0, stream>>>(x, emb, xe);
  lstm_scan<<<128, 512, 0, stream>>>(xe, Wp0, Wp1, b0p, b1p, h1r, h2r, c2, seqb);
  outproj<<<1, 640, 0, stream>>>(c2, Wout, bout, out);
}